// Round 2
// baseline (647.649 us; speedup 1.0000x reference)
//
#include <hip/hip_runtime.h>

#define BNH 32
#define L 1024
#define D 64
#define RP 129
#define CLIPV 64
#define TI 16
#define TJ 128
#define NJT (L / TJ)
#define NT 256
#define SS 1032      // fp16 score-tile stride (2064 B rows: 16B-aligned)
#define KST 72       // k tile stride (halves), 144 B rows
#define VST 136      // vT tile stride (halves), 272 B rows

typedef __attribute__((ext_vector_type(8))) short bf16x8;
typedef __attribute__((ext_vector_type(4))) float f32x4;
typedef __attribute__((ext_vector_type(8))) _Float16 f16x8;
typedef __attribute__((ext_vector_type(4))) _Float16 f16x4;

__device__ __forceinline__ unsigned short f2bf(float f) {
    unsigned int u = __builtin_bit_cast(unsigned int, f);
    return (unsigned short)((u + 0x7fffu + ((u >> 16) & 1u)) >> 16);
}

// Single fused kernel:
//  prologue: stage pos, q (fp32 + bf16); compute qe[16][129] in fp32 (replaces qe_kernel)
//  pass A  : QK^T (bf16 MFMA) + qe + attn_w, /8, mask -> fp16 scores in LDS; track row max
//  pass B1 : e = exp(s-m) from LDS scores; l, av run-length scatter, PV via MFMA (V^T in LDS)
//  pass B2 : p = exp(s-m)*il from LDS scores -> single coalesced global write
//  epilogue: out = (PV + av @ emb_v) * il
__global__ __launch_bounds__(NT, 2) void attn_fused(
    const float* __restrict__ q, const float* __restrict__ k, const float* __restrict__ v,
    const float* __restrict__ attn_w, const float* __restrict__ emb_k,
    const float* __restrict__ emb_v, const int* __restrict__ pos,
    const unsigned char* __restrict__ mask,
    float* __restrict__ out, float* __restrict__ p_out) {

    __shared__ __attribute__((aligned(16))) _Float16 s_lds[TI][SS];        // 33024 B
    __shared__ __attribute__((aligned(16))) unsigned short kv_u[TJ * KST]; // 18432 B (k tile / vT 64x136)
    __shared__ __attribute__((aligned(16))) unsigned short q_u[TI * KST];  // 2304 B
    __shared__ unsigned short pos_s[L];                                    // 2048 B
    __shared__ float qeav_s[TI * RP];        // 8256 B: qe (pass A) then av (pass B)
    __shared__ __attribute__((aligned(16))) float qfout_s[TI * 68];        // 4352 B: q fp32 then out partials
    __shared__ float m_part[4][16];
    __shared__ float m_s[16];
    __shared__ float l_s[16];

    const int tid = threadIdx.x;
    // XCD-aware swizzle (2048 % 8 == 0 -> bijective): each XCD gets a contiguous wg chunk
    const int wg = ((int)blockIdx.x & 7) * ((BNH * (L / TI)) >> 3) + ((int)blockIdx.x >> 3);
    const int b = wg >> 6;
    const int i0 = (wg & 63) * TI;
    const int w = tid >> 6;          // wave 0..3
    const int lane = tid & 63;
    const int quad = lane >> 4;
    const int lo = lane & 15;

    // ---- prologue staging ----
    for (int t = tid; t < L; t += NT) pos_s[t] = (unsigned short)pos[b * L + t];
    {   // q rows fp32 -> qfout_s (one float4 per thread)
        const int row = tid >> 4, c4 = tid & 15;
        *reinterpret_cast<float4*>(&qfout_s[row * 68 + c4 * 4]) =
            *reinterpret_cast<const float4*>(q + ((size_t)(b * L + i0 + row)) * D + c4 * 4);
    }
    if (tid < TI * 8) {   // q rows bf16 -> q_u
        const int r = tid >> 3, dc = tid & 7;
        const float* src = q + ((size_t)(b * L + i0 + r)) * D + dc * 8;
        float4 f0 = *(const float4*)src;
        float4 f1 = *(const float4*)(src + 4);
        bf16x8 qq;
        qq[0] = (short)f2bf(f0.x); qq[1] = (short)f2bf(f0.y);
        qq[2] = (short)f2bf(f0.z); qq[3] = (short)f2bf(f0.w);
        qq[4] = (short)f2bf(f1.x); qq[5] = (short)f2bf(f1.y);
        qq[6] = (short)f2bf(f1.z); qq[7] = (short)f2bf(f1.w);
        *(bf16x8*)&q_u[r * KST + dc * 8] = qq;
    }
    __syncthreads();

    // ---- fused qe: qe[row][r] = dot(q[row], emb_k[r]) in fp32 (emb_k is L2-hot, 33 KB) ----
    {
        const int row = tid >> 4, rr = tid & 15;
        for (int r = rr; r < RP; r += 16) {
            float acc = 0.f;
#pragma unroll
            for (int d4 = 0; d4 < 16; ++d4) {
                float4 qv = *reinterpret_cast<const float4*>(&qfout_s[row * 68 + d4 * 4]);
                float4 ev = *reinterpret_cast<const float4*>(emb_k + r * D + d4 * 4);
                acc += qv.x * ev.x + qv.y * ev.y + qv.z * ev.z + qv.w * ev.w;
            }
            qeav_s[row * RP + r] = acc;
        }
    }
    __syncthreads();

    // q A-fragments: lane supplies A row m = lo, k-chunk = quad*8 (+32 for second kc)
    const bf16x8 aq0 = *(const bf16x8*)&q_u[lo * KST + quad * 8];
    const bf16x8 aq1 = *(const bf16x8*)&q_u[lo * KST + 32 + quad * 8];

    int posA[4];
#pragma unroll
    for (int r = 0; r < 4; ++r) posA[r] = (int)pos_s[i0 + quad * 4 + r];

    // ---- pass A: scores -> fp16 LDS, track row max ----
    float mA[4] = {-3e38f, -3e38f, -3e38f, -3e38f};
    for (int jt = 0; jt < NJT; ++jt) {
        const int j0 = jt * TJ;
#pragma unroll
        for (int s = 0; s < 4; ++s) {   // stage 128x64 k tile as bf16
            int ch = s * NT + tid;
            int col = ch >> 3, dc = ch & 7;
            const float* src = k + ((size_t)(b * L + j0 + col)) * D + dc * 8;
            float4 f0 = *(const float4*)src;
            float4 f1 = *(const float4*)(src + 4);
            bf16x8 kk;
            kk[0] = (short)f2bf(f0.x); kk[1] = (short)f2bf(f0.y);
            kk[2] = (short)f2bf(f0.z); kk[3] = (short)f2bf(f0.w);
            kk[4] = (short)f2bf(f1.x); kk[5] = (short)f2bf(f1.y);
            kk[6] = (short)f2bf(f1.z); kk[7] = (short)f2bf(f1.w);
            *(bf16x8*)&kv_u[col * KST + dc * 8] = kk;
        }
        __syncthreads();
#pragma unroll
        for (int ct = 0; ct < 2; ++ct) {
            const int ncol = w * 32 + ct * 16 + lo;
            const int j = j0 + ncol;
            bf16x8 b0 = *(const bf16x8*)&kv_u[ncol * KST + quad * 8];
            bf16x8 b1 = *(const bf16x8*)&kv_u[ncol * KST + 32 + quad * 8];
            f32x4 acc = {0.f, 0.f, 0.f, 0.f};
            acc = __builtin_amdgcn_mfma_f32_16x16x32_bf16(aq0, b0, acc, 0, 0, 0);
            acc = __builtin_amdgcn_mfma_f32_16x16x32_bf16(aq1, b1, acc, 0, 0, 0);
            const int pj = (int)pos_s[j];
#pragma unroll
            for (int r = 0; r < 4; ++r) {
                const int row = quad * 4 + r;
                const size_t grow = (size_t)(b * L + i0 + row) * L + j;
                int dd = pj - posA[r];
                dd = min(max(dd, -CLIPV), CLIPV) + CLIPV;
                float sc = (acc[r] + qeav_s[row * RP + dd] + attn_w[grow]) * 0.125f;
                if (mask[grow]) sc = -3e38f;
                mA[r] = fmaxf(mA[r], sc);
                s_lds[row][j] = (_Float16)sc;
            }
        }
        __syncthreads();
    }

    // ---- row-max reduction; re-purpose qe->av and qf->out (zero-init) ----
#pragma unroll
    for (int off = 1; off < 16; off <<= 1) {
#pragma unroll
        for (int r = 0; r < 4; ++r) mA[r] = fmaxf(mA[r], __shfl_xor(mA[r], off, 64));
    }
    if (lo == 0) {
#pragma unroll
        for (int r = 0; r < 4; ++r) m_part[w][quad * 4 + r] = mA[r];
    }
    __syncthreads();
    if (tid < 16) {
        m_s[tid] = fmaxf(fmaxf(m_part[0][tid], m_part[1][tid]),
                         fmaxf(m_part[2][tid], m_part[3][tid]));
        l_s[tid] = 0.f;
    }
    for (int t = tid; t < TI * RP; t += NT) qeav_s[t] = 0.f;
    for (int t = tid; t < TI * 68; t += NT) qfout_s[t] = 0.f;
    __syncthreads();

    // ---- pass B1: e = exp(s-m) from LDS; l, av scatter, PV ----
    const float mrow = m_s[lo];              // A row m = lo
    const int pos_m = (int)pos_s[i0 + lo];
    float l_r = 0.f;
    f32x4 oc[4];
#pragma unroll
    for (int ct = 0; ct < 4; ++ct) { oc[ct][0]=0.f; oc[ct][1]=0.f; oc[ct][2]=0.f; oc[ct][3]=0.f; }

    for (int jt = 0; jt < NJT; ++jt) {
        const int j0 = jt * TJ;
        const int colv = tid & 127, hv = tid >> 7;
        const float* srcv = v + ((size_t)(b * L + j0 + colv)) * D + hv * 32;
        float4 vf[8];
#pragma unroll
        for (int s = 0; s < 8; ++s) vf[s] = *(const float4*)(srcv + s * 4);   // issue before barrier (T14)
        __syncthreads();   // prev tile's kv_u readers done
#pragma unroll
        for (int s = 0; s < 8; ++s) {   // vT[d][col] bf16, stride 136
            const int dbase = hv * 32 + s * 4;
            kv_u[(dbase + 0) * VST + colv] = f2bf(vf[s].x);
            kv_u[(dbase + 1) * VST + colv] = f2bf(vf[s].y);
            kv_u[(dbase + 2) * VST + colv] = f2bf(vf[s].z);
            kv_u[(dbase + 3) * VST + colv] = f2bf(vf[s].w);
        }
        __syncthreads();

        const int jcol = j0 + w * 32 + quad * 8;
        f16x8 sv = *reinterpret_cast<const f16x8*>(&s_lds[lo][jcol]);
        float ev[8];
#pragma unroll
        for (int i = 0; i < 8; ++i) ev[i] = __expf((float)sv[i] - mrow);
        l_r += ev[0] + ev[1] + ev[2] + ev[3] + ev[4] + ev[5] + ev[6] + ev[7];
        // av scatter: run-length compressed (pos sorted => dd monotone in j)
        int cur = -1; float a = 0.f;
#pragma unroll
        for (int i = 0; i < 8; ++i) {
            int dd = (int)pos_s[jcol + i] - pos_m;
            dd = min(max(dd, -CLIPV), CLIPV) + CLIPV;
            if (dd != cur) {
                if (cur >= 0) atomicAdd(&qeav_s[lo * RP + cur], a);
                cur = dd; a = 0.f;
            }
            a += ev[i];
        }
        atomicAdd(&qeav_s[lo * RP + cur], a);
        bf16x8 af;
#pragma unroll
        for (int i = 0; i < 8; ++i) af[i] = (short)f2bf(ev[i]);
#pragma unroll
        for (int ct = 0; ct < 4; ++ct) {
            bf16x8 bf = *reinterpret_cast<const bf16x8*>(
                &kv_u[(ct * 16 + lo) * VST + w * 32 + quad * 8]);
            oc[ct] = __builtin_amdgcn_mfma_f32_16x16x32_bf16(af, bf, oc[ct], 0, 0, 0);
        }
    }

    // unnormalized PV partials -> qfout_s; l -> l_s
#pragma unroll
    for (int ct = 0; ct < 4; ++ct) {
#pragma unroll
        for (int r = 0; r < 4; ++r)
            atomicAdd(&qfout_s[(quad * 4 + r) * 68 + ct * 16 + lo], oc[ct][r]);
    }
    l_r += __shfl_xor(l_r, 16, 64);
    l_r += __shfl_xor(l_r, 32, 64);
    if (lane < 16) atomicAdd(&l_s[lo], l_r);
    __syncthreads();
    if (tid < 16) l_s[tid] = 1.f / l_s[tid];
    __syncthreads();

    // ---- pass B2: p = exp(s-m)*il from LDS scores -> single coalesced write ----
#pragma unroll
    for (int s = 0; s < TI; ++s) {
        f16x4 sv = *reinterpret_cast<const f16x4*>(&s_lds[s][tid * 4]);
        const float mm = m_s[s], il = l_s[s];
        float4 pv;
        pv.x = __expf((float)sv[0] - mm) * il;
        pv.y = __expf((float)sv[1] - mm) * il;
        pv.z = __expf((float)sv[2] - mm) * il;
        pv.w = __expf((float)sv[3] - mm) * il;
        *reinterpret_cast<float4*>(p_out + (size_t)(b * L + i0 + s) * L + tid * 4) = pv;
    }

    // ---- epilogue: out = (PV + av @ emb_v) * inv_l ----
    {
        const int row = tid >> 4, dc = tid & 15;
        float4 o = *(const float4*)&qfout_s[row * 68 + dc * 4];
        const float il = l_s[row];
        for (int r = 0; r < RP; ++r) {
            float a = qeav_s[row * RP + r];
            if (a != 0.f) {
                const float4 ev4 = *(const float4*)(emb_v + r * D + dc * 4);
                o.x += a * ev4.x; o.y += a * ev4.y;
                o.z += a * ev4.z; o.w += a * ev4.w;
            }
        }
        o.x *= il; o.y *= il; o.z *= il; o.w *= il;
        *(float4*)(out + (size_t)(b * L + i0 + row) * D + dc * 4) = o;
    }
}

extern "C" void kernel_launch(void* const* d_in, const int* in_sizes, int n_in,
                              void* d_out, int out_size, void* d_ws, size_t ws_size,
                              hipStream_t stream) {
    const float* q = (const float*)d_in[0];
    const float* k = (const float*)d_in[1];
    const float* v = (const float*)d_in[2];
    const float* attn_w = (const float*)d_in[3];
    const float* emb_k = (const float*)d_in[4];
    const float* emb_v = (const float*)d_in[5];
    const int* pos = (const int*)d_in[6];
    const unsigned char* mask = (const unsigned char*)d_in[7];
    float* out = (float*)d_out;
    float* p_out = out + (size_t)BNH * L * D;   // p region of d_out

    attn_fused<<<BNH * (L / TI), NT, 0, stream>>>(q, k, v, attn_w, emb_k, emb_v,
                                                  pos, mask, out, p_out);
}

// Round 3
// 538.267 us; speedup vs baseline: 1.2032x; 1.2032x over previous
//
#include <hip/hip_runtime.h>

#define BNH 32
#define L 1024
#define D 64
#define RP 129
#define CLIPV 64
#define TI 16
#define TJ 64
#define NJT (L / TJ)      // 16
#define NT 256
#define SS 1032           // score stride (halves); 2064B rows: 16B-aligned, banks spread
#define KVST 72           // pass-A k-tile stride (halves) within wave-private region
#define VTST 40           // pass-B vT stride (halves) within wave-private region

typedef __attribute__((ext_vector_type(8))) short bf16x8;
typedef __attribute__((ext_vector_type(4))) float f32x4;
typedef __attribute__((ext_vector_type(8))) _Float16 f16x8;
typedef __attribute__((ext_vector_type(4))) _Float16 f16x4;

__device__ __forceinline__ unsigned short f2bf(float f) {
    unsigned int u = __builtin_bit_cast(unsigned int, f);
    return (unsigned short)((u + 0x7fffu + ((u >> 16) & 1u)) >> 16);
}

// LDS layout (53,952 B total -> 3 blocks/CU):
//   0      s_h fp16[16][1032] scores   | prologue: q fp32[16][68] | epilogue: emb_v fp32[129][64]
//   33024  kv  u16, 4 x 2560B wave-private (A: k[16][72]; B1: vT[32][40]) | epilogue: buf0/buf1 fp32[16][68]
//   43264  qeav fp32[16][129]  (qe in pass A, av in pass B)
//   51520  pos u16[1024]
//   53568  m_part fp32[4][16]
//   53824  m_s fp32[16]
//   53888  l_s fp32[16]
__global__ __launch_bounds__(NT, 3) void attn_fused(
    const float* __restrict__ q, const float* __restrict__ k, const float* __restrict__ v,
    const float* __restrict__ attn_w, const float* __restrict__ emb_k,
    const float* __restrict__ emb_v, const int* __restrict__ pos,
    const unsigned char* __restrict__ mask,
    float* __restrict__ out, float* __restrict__ p_out) {

    __shared__ __attribute__((aligned(16))) char smem[53952];
    _Float16* s_h = (_Float16*)smem;
    float* qf = (float*)smem;                              // prologue overlay
    float* embv = (float*)smem;                            // epilogue overlay
    unsigned short* kv = (unsigned short*)(smem + 33024);
    float* buf0 = (float*)(smem + 33024);                  // epilogue overlay
    float* buf1 = (float*)(smem + 37376);
    float* qeav = (float*)(smem + 43264);
    unsigned short* pos_s = (unsigned short*)(smem + 51520);
    float* m_part = (float*)(smem + 53568);
    float* m_s = (float*)(smem + 53824);
    float* l_s = (float*)(smem + 53888);

    const int tid = threadIdx.x;
    const int wg = ((int)blockIdx.x & 7) * ((BNH * (L / TI)) >> 3) + ((int)blockIdx.x >> 3);
    const int b = wg >> 6;
    const int i0 = (wg & 63) * TI;
    const int w = tid >> 6;
    const int lane = tid & 63;
    const int quad = lane >> 4;
    const int lo = lane & 15;
    unsigned short* kvw = kv + w * 1280;   // wave-private 2560 B

    // ---- prologue: pos + q fp32 (into score region) ----
    for (int t = tid; t < L; t += NT) pos_s[t] = (unsigned short)pos[b * L + t];
    {
        const int row = tid >> 4, c4 = tid & 15;
        *reinterpret_cast<float4*>(&qf[row * 68 + c4 * 4]) =
            *reinterpret_cast<const float4*>(q + ((size_t)(b * L + i0 + row)) * D + c4 * 4);
    }
    __syncthreads();

    // qe[row][r] = dot(q[row], emb_k[r]) fp32 (emb_k L2-hot, 33 KB)
    {
        const int row = tid >> 4, rr = tid & 15;
        for (int r = rr; r < RP; r += 16) {
            float acc = 0.f;
#pragma unroll
            for (int d4 = 0; d4 < 16; ++d4) {
                float4 qv = *reinterpret_cast<const float4*>(&qf[row * 68 + d4 * 4]);
                float4 ev = *reinterpret_cast<const float4*>(emb_k + r * D + d4 * 4);
                acc += qv.x * ev.x + qv.y * ev.y + qv.z * ev.z + qv.w * ev.w;
            }
            qeav[row * RP + r] = acc;
        }
    }

    // Q A-fragments straight from global (no LDS): row lo, k-chunks quad*8 / +32
    bf16x8 aq0, aq1;
    {
        const float* qrow = q + (size_t)(b * L + i0 + lo) * D + quad * 8;
        float4 a0 = *(const float4*)qrow, a1 = *(const float4*)(qrow + 4);
        float4 a2 = *(const float4*)(qrow + 32), a3 = *(const float4*)(qrow + 36);
        aq0[0] = (short)f2bf(a0.x); aq0[1] = (short)f2bf(a0.y);
        aq0[2] = (short)f2bf(a0.z); aq0[3] = (short)f2bf(a0.w);
        aq0[4] = (short)f2bf(a1.x); aq0[5] = (short)f2bf(a1.y);
        aq0[6] = (short)f2bf(a1.z); aq0[7] = (short)f2bf(a1.w);
        aq1[0] = (short)f2bf(a2.x); aq1[1] = (short)f2bf(a2.y);
        aq1[2] = (short)f2bf(a2.z); aq1[3] = (short)f2bf(a2.w);
        aq1[4] = (short)f2bf(a3.x); aq1[5] = (short)f2bf(a3.y);
        aq1[6] = (short)f2bf(a3.z); aq1[7] = (short)f2bf(a3.w);
    }
    int posA[4];
#pragma unroll
    for (int r = 0; r < 4; ++r) posA[r] = (int)pos_s[i0 + quad * 4 + r];
    __syncthreads();   // qf dead; qe ready; scores may now be written

    // ---- pass A: barrier-free, wave-private K staging, 1-ahead pipelined ----
    float mA[4] = {-3e38f, -3e38f, -3e38f, -3e38f};

    auto LOADA = [&](float4* kr, float* awr, int* mkr, int jt) {
        const int j0 = jt * TJ;
        const int jj = j0 + w * 16 + lo;
#pragma unroll
        for (int r = 0; r < 4; ++r) {
            const size_t grow = (size_t)(b * L + i0 + quad * 4 + r) * L + jj;
            awr[r] = attn_w[grow];
            mkr[r] = (int)mask[grow];
        }
#pragma unroll
        for (int c = 0; c < 2; ++c) {
            const int ch = c * 64 + lane;
            const int col = ch >> 3, dc = ch & 7;
            const float* src = k + ((size_t)(b * L + j0 + w * 16 + col)) * D + dc * 8;
            kr[c * 2 + 0] = *(const float4*)src;
            kr[c * 2 + 1] = *(const float4*)(src + 4);
        }
    };
    auto PROCA = [&](const float4* kr, const float* awr, const int* mkr, int jt) {
        const int j0 = jt * TJ;
#pragma unroll
        for (int c = 0; c < 2; ++c) {
            const int ch = c * 64 + lane;
            const int col = ch >> 3, dc = ch & 7;
            bf16x8 kk;
            kk[0] = (short)f2bf(kr[c * 2].x);     kk[1] = (short)f2bf(kr[c * 2].y);
            kk[2] = (short)f2bf(kr[c * 2].z);     kk[3] = (short)f2bf(kr[c * 2].w);
            kk[4] = (short)f2bf(kr[c * 2 + 1].x); kk[5] = (short)f2bf(kr[c * 2 + 1].y);
            kk[6] = (short)f2bf(kr[c * 2 + 1].z); kk[7] = (short)f2bf(kr[c * 2 + 1].w);
            *(bf16x8*)&kvw[col * KVST + dc * 8] = kk;
        }
        bf16x8 b0 = *(const bf16x8*)&kvw[lo * KVST + quad * 8];
        bf16x8 b1 = *(const bf16x8*)&kvw[lo * KVST + 32 + quad * 8];
        f32x4 acc = {0.f, 0.f, 0.f, 0.f};
        acc = __builtin_amdgcn_mfma_f32_16x16x32_bf16(aq0, b0, acc, 0, 0, 0);
        acc = __builtin_amdgcn_mfma_f32_16x16x32_bf16(aq1, b1, acc, 0, 0, 0);
        const int j = j0 + w * 16 + lo;
        const int pj = (int)pos_s[j];
#pragma unroll
        for (int r = 0; r < 4; ++r) {
            const int row = quad * 4 + r;
            int dd = pj - posA[r];
            dd = min(max(dd, -CLIPV), CLIPV) + CLIPV;
            float sc = (acc[r] + qeav[row * RP + dd] + awr[r]) * 0.125f;
            if (mkr[r]) sc = -3e38f;
            mA[r] = fmaxf(mA[r], sc);
            s_h[row * SS + j] = (_Float16)sc;
        }
    };

    {
        float4 krA[4], krB[4];
        float awA[4], awB[4];
        int mkA[4], mkB[4];
        LOADA(krA, awA, mkA, 0);
        for (int jt = 0; jt < NJT; jt += 2) {
            LOADA(krB, awB, mkB, jt + 1);
            PROCA(krA, awA, mkA, jt);
            if (jt + 2 < NJT) LOADA(krA, awA, mkA, jt + 2);
            PROCA(krB, awB, mkB, jt + 1);
        }
    }

    // ---- row-max reduction; zero av, l ----
#pragma unroll
    for (int off = 1; off < 16; off <<= 1) {
#pragma unroll
        for (int r = 0; r < 4; ++r) mA[r] = fmaxf(mA[r], __shfl_xor(mA[r], off, 64));
    }
    if (lo == 0) {
#pragma unroll
        for (int r = 0; r < 4; ++r) m_part[w * 16 + quad * 4 + r] = mA[r];
    }
    __syncthreads();
    if (tid < 16) {
        m_s[tid] = fmaxf(fmaxf(m_part[tid], m_part[16 + tid]),
                         fmaxf(m_part[32 + tid], m_part[48 + tid]));
        l_s[tid] = 0.f;
    }
    for (int t = tid; t < TI * RP; t += NT) qeav[t] = 0.f;
    __syncthreads();

    // ---- pass B1: barrier-free, wave-private V quadrant, 1-ahead pipelined ----
    // wave w: j-half (w&1)*32, d-half (w>>1)*32; waves 0,1 own l/av (each j once)
    const float mrow = m_s[lo];
    const int pos_m = (int)pos_s[i0 + lo];
    float l_r = 0.f;
    f32x4 oc[2];
    oc[0][0]=0.f; oc[0][1]=0.f; oc[0][2]=0.f; oc[0][3]=0.f;
    oc[1][0]=0.f; oc[1][1]=0.f; oc[1][2]=0.f; oc[1][3]=0.f;
    const int jhw = (w & 1) * 32, dhw = (w >> 1) * 32;

    auto LOADB = [&](float4* vr, int jt) {
        const int j0 = jt * TJ + jhw;
#pragma unroll
        for (int c = 0; c < 4; ++c) {
            const int ch = c * 64 + lane;
            const int jl = ch >> 3, c4 = ch & 7;
            vr[c] = *(const float4*)(v + ((size_t)(b * L + j0 + jl)) * D + dhw + c4 * 4);
        }
    };
    auto PROCB = [&](const float4* vr, int jt) {
#pragma unroll
        for (int c = 0; c < 4; ++c) {
            const int ch = c * 64 + lane;
            const int jl = ch >> 3, c4 = ch & 7;
            kvw[(c4 * 4 + 0) * VTST + jl] = f2bf(vr[c].x);
            kvw[(c4 * 4 + 1) * VTST + jl] = f2bf(vr[c].y);
            kvw[(c4 * 4 + 2) * VTST + jl] = f2bf(vr[c].z);
            kvw[(c4 * 4 + 3) * VTST + jl] = f2bf(vr[c].w);
        }
        const int jcol = jt * TJ + jhw + quad * 8;
        f16x8 sv = *(const f16x8*)&s_h[lo * SS + jcol];
        float ev[8];
#pragma unroll
        for (int i = 0; i < 8; ++i) ev[i] = __expf((float)sv[i] - mrow);
        if (w < 2) {
            l_r += ev[0] + ev[1] + ev[2] + ev[3] + ev[4] + ev[5] + ev[6] + ev[7];
            int cur = -1; float a = 0.f;
#pragma unroll
            for (int i = 0; i < 8; ++i) {
                int dd = (int)pos_s[jcol + i] - pos_m;
                dd = min(max(dd, -CLIPV), CLIPV) + CLIPV;
                if (dd != cur) {
                    if (cur >= 0) atomicAdd(&qeav[lo * RP + cur], a);
                    cur = dd; a = 0.f;
                }
                a += ev[i];
            }
            atomicAdd(&qeav[lo * RP + cur], a);
        }
        bf16x8 af;
#pragma unroll
        for (int i = 0; i < 8; ++i) af[i] = (short)f2bf(ev[i]);
#pragma unroll
        for (int ct = 0; ct < 2; ++ct) {
            bf16x8 bf = *(const bf16x8*)&kvw[(ct * 16 + lo) * VTST + quad * 8];
            oc[ct] = __builtin_amdgcn_mfma_f32_16x16x32_bf16(af, bf, oc[ct], 0, 0, 0);
        }
    };

    {
        float4 vrA[4], vrB[4];
        LOADB(vrA, 0);
        for (int jt = 0; jt < NJT; jt += 2) {
            LOADB(vrB, jt + 1);
            PROCB(vrA, jt);
            if (jt + 2 < NJT) LOADB(vrA, jt + 2);
            PROCB(vrB, jt + 1);
        }
    }

    // ---- l reduction ----
    l_r += __shfl_xor(l_r, 16, 64);
    l_r += __shfl_xor(l_r, 32, 64);
    if (w < 2 && lane < 16) atomicAdd(&l_s[lo], l_r);
    __syncthreads();
    if (tid < 16) l_s[tid] = 1.f / l_s[tid];
    __syncthreads();

    // ---- pass B2: p = exp(s-m)*il -> single coalesced write ----
#pragma unroll
    for (int s = 0; s < TI; ++s) {
        f16x4 sv = *reinterpret_cast<const f16x4*>(&s_h[s * SS + tid * 4]);
        const float mm = m_s[s], il = l_s[s];
        float4 pv;
        pv.x = __expf((float)sv[0] - mm) * il;
        pv.y = __expf((float)sv[1] - mm) * il;
        pv.z = __expf((float)sv[2] - mm) * il;
        pv.w = __expf((float)sv[3] - mm) * il;
        *reinterpret_cast<float4*>(p_out + (size_t)(b * L + i0 + s) * L + tid * 4) = pv;
    }
    __syncthreads();   // s_h readers done; kv readers long done

    // ---- epilogue: emb_v fp32 -> score region; oc partials -> buf0/buf1 ----
    for (int t = tid; t < RP * 16; t += NT) {
        const int r = t >> 4, c4 = t & 15;
        *reinterpret_cast<float4*>(&embv[r * 64 + c4 * 4]) =
            *reinterpret_cast<const float4*>(emb_v + r * D + c4 * 4);
    }
    {
        float* bufw = (w & 1) ? buf1 : buf0;
#pragma unroll
        for (int ct = 0; ct < 2; ++ct) {
#pragma unroll
            for (int r = 0; r < 4; ++r)
                bufw[(quad * 4 + r) * 68 + dhw + ct * 16 + lo] = oc[ct][r];
        }
    }
    __syncthreads();

    // out = (PV + av @ emb_v) * inv_l
    {
        const int row = tid >> 4, dc = tid & 15;
        float4 o0 = *(const float4*)&buf0[row * 68 + dc * 4];
        float4 o1 = *(const float4*)&buf1[row * 68 + dc * 4];
        float4 o;
        o.x = o0.x + o1.x; o.y = o0.y + o1.y; o.z = o0.z + o1.z; o.w = o0.w + o1.w;
        const float il = l_s[row];
#pragma unroll 4
        for (int r = 0; r < RP; ++r) {
            const float a = qeav[row * RP + r];
            const float4 ev4 = *(const float4*)&embv[r * 64 + dc * 4];
            o.x += a * ev4.x; o.y += a * ev4.y;
            o.z += a * ev4.z; o.w += a * ev4.w;
        }
        o.x *= il; o.y *= il; o.z *= il; o.w *= il;
        *(float4*)(out + (size_t)(b * L + i0 + row) * D + dc * 4) = o;
    }
}

extern "C" void kernel_launch(void* const* d_in, const int* in_sizes, int n_in,
                              void* d_out, int out_size, void* d_ws, size_t ws_size,
                              hipStream_t stream) {
    const float* q = (const float*)d_in[0];
    const float* k = (const float*)d_in[1];
    const float* v = (const float*)d_in[2];
    const float* attn_w = (const float*)d_in[3];
    const float* emb_k = (const float*)d_in[4];
    const float* emb_v = (const float*)d_in[5];
    const int* pos = (const int*)d_in[6];
    const unsigned char* mask = (const unsigned char*)d_in[7];
    float* out = (float*)d_out;
    float* p_out = out + (size_t)BNH * L * D;

    attn_fused<<<BNH * (L / TI), NT, 0, stream>>>(q, k, v, attn_w, emb_k, emb_v,
                                                  pos, mask, out, p_out);
}